// Round 2
// baseline (995.928 us; speedup 1.0000x reference)
//
#include <hip/hip_runtime.h>
#include <hip/hip_bf16.h>

// Problem constants
constexpr int NH  = 12;    // heads
constexpr int SEQ = 2048;  // sequence
constexpr int DHD = 64;    // head dim
constexpr int DIM = 768;   // model dim
// B = 2, GAMMA = 0.5, SCALE*SMOOTHING = 0.125 (folded into Q projections)

typedef __bf16 bf16x8 __attribute__((ext_vector_type(8)));
typedef __bf16 bf16x4 __attribute__((ext_vector_type(4)));
typedef float  f32x4  __attribute__((ext_vector_type(4)));

#define MFMA16(a, b, c) __builtin_amdgcn_mfma_f32_16x16x32_bf16((a), (b), (c), 0, 0, 0)

// ---------------------------------------------------------------------------
// Kernel 1: projections with LDS-staged coalesced epilogue.
//   mode 0: out[((b*NH+h)*SEQ+s)*DHD+d]   (Qi / Ki)
//   mode 1: out[((b*NH+h)*DHD+d)*SEQ+s]   (V transposed)
//   mode 2: out[(h*SEQ+s)*DHD+d]          (Qp / Kp)
// Tile: BM=64, BN=192, BK=32; 4 waves 2x2. Output tile re-staged transposed
// in LDS (oT[192][72], aliases Al/Wl) then written in >=16B contiguous chunks.
// ---------------------------------------------------------------------------
__global__ __launch_bounds__(256) void proj_kernel(
    const float* __restrict__ inp, const float* __restrict__ pos,
    const float* __restrict__ Wqi, const float* __restrict__ Wki,
    const float* __restrict__ Wqp, const float* __restrict__ Wkp,
    const float* __restrict__ Wvv,
    __bf16* __restrict__ Qi, __bf16* __restrict__ Ki, __bf16* __restrict__ Vt,
    __bf16* __restrict__ Qp, __bf16* __restrict__ Kp)
{
    const int z = blockIdx.z;
    const float* A; const float* W; __bf16* outp; int M; int mode; float scale = 1.0f;
    if (z == 0)      { A = inp; W = Wqi; outp = Qi; M = 4096; mode = 0; scale = 0.125f; }
    else if (z == 1) { A = inp; W = Wki; outp = Ki; M = 4096; mode = 0; }
    else if (z == 2) { A = inp; W = Wvv; outp = Vt; M = 4096; mode = 1; }
    else if (z == 3) { A = pos; W = Wqp; outp = Qp; M = 2048; mode = 2; scale = 0.125f; }
    else             { A = pos; W = Wkp; outp = Kp; M = 2048; mode = 2; }

    const int m0 = blockIdx.y * 64;
    if (m0 >= M) return;
    const int n0 = blockIdx.x * 192;

    __shared__ __align__(16) char smraw[27648];
    auto Al = reinterpret_cast<__bf16(*)[32]>(smraw);           // [64][32]
    auto Wl = reinterpret_cast<__bf16(*)[32]>(smraw + 4096);    // [192][32]
    auto oT = reinterpret_cast<__bf16(*)[72]>(smraw);           // [192][72] (aliases above)

    const int tid = threadIdx.x;
    const int lane = tid & 63, wv = tid >> 6;
    const int wm = wv >> 1, wn = wv & 1;
    const int l15 = lane & 15, lg = lane >> 4;

    f32x4 c[2][6] = {};

    for (int kt = 0; kt < 24; ++kt) {
        const int k0 = kt * 32;
        __syncthreads();
        {   // stage A tile 64x32 (f32 -> bf16)
            const int r = tid >> 3, kq = tid & 7;
            #pragma unroll
            for (int rep = 0; rep < 2; ++rep) {
                const float4 v = *reinterpret_cast<const float4*>(
                    &A[(size_t)(m0 + r + rep * 32) * DIM + k0 + kq * 4]);
                bf16x4 t;
                t[0] = (__bf16)v.x; t[1] = (__bf16)v.y; t[2] = (__bf16)v.z; t[3] = (__bf16)v.w;
                *reinterpret_cast<bf16x4*>(&Al[r + rep * 32][kq * 4]) = t;
            }
        }
        for (int idx = tid; idx < 32 * 48; idx += 256) {
            const int k = idx / 48, nq = idx - k * 48;
            const float4 v = *reinterpret_cast<const float4*>(
                &W[(size_t)(k0 + k) * DIM + n0 + nq * 4]);
            Wl[nq * 4 + 0][k] = (__bf16)v.x;
            Wl[nq * 4 + 1][k] = (__bf16)v.y;
            Wl[nq * 4 + 2][k] = (__bf16)v.z;
            Wl[nq * 4 + 3][k] = (__bf16)v.w;
        }
        __syncthreads();

        bf16x8 a[2], b[6];
        #pragma unroll
        for (int mf = 0; mf < 2; ++mf)
            a[mf] = *reinterpret_cast<const bf16x8*>(&Al[wm * 32 + mf * 16 + l15][lg * 8]);
        #pragma unroll
        for (int nf = 0; nf < 6; ++nf)
            b[nf] = *reinterpret_cast<const bf16x8*>(&Wl[wn * 96 + nf * 16 + l15][lg * 8]);
        #pragma unroll
        for (int mf = 0; mf < 2; ++mf)
            #pragma unroll
            for (int nf = 0; nf < 6; ++nf)
                c[mf][nf] = MFMA16(a[mf], b[nf], c[mf][nf]);
    }

    // stage output tile transposed: oT[n_local][m_local]
    __syncthreads();
    #pragma unroll
    for (int mf = 0; mf < 2; ++mf)
        #pragma unroll
        for (int nf = 0; nf < 6; ++nf) {
            bf16x4 t;
            #pragma unroll
            for (int r = 0; r < 4; ++r) t[r] = (__bf16)(c[mf][nf][r] * scale);
            *reinterpret_cast<bf16x4*>(&oT[wn * 96 + nf * 16 + l15][wm * 32 + mf * 16 + lg * 4]) = t;
        }
    __syncthreads();

    if (mode == 1) {
        // Vt rows: (h,d) -> 64 contiguous s (128 B)
        if (tid < 192) {
            const int nl = tid;
            const int h = nl % 12, d = (n0 / 12) + nl / 12;
            const int b_ = m0 >> 11, s0 = m0 & 2047;
            const size_t base = (((size_t)b_ * NH + h) * DHD + d) * SEQ + s0;
            #pragma unroll
            for (int q = 0; q < 8; ++q)
                *reinterpret_cast<bf16x8*>(&outp[base + q * 8]) =
                    *reinterpret_cast<const bf16x8*>(&oT[nl][q * 8]);
        }
    } else {
        // [.,h,s,d] rows: (s,h) -> 16 contiguous d (32 B)
        const int d0 = n0 / 12;
        #pragma unroll
        for (int rep = 0; rep < 3; ++rep) {
            const int cc = rep * 256 + tid;
            const int s = cc / 12, h = cc - s * 12;
            size_t base;
            if (mode == 0) {
                const int b_ = m0 >> 11, sg = (m0 & 2047) + s;
                base = (((size_t)b_ * NH + h) * SEQ + sg) * DHD + d0;
            } else {
                base = ((size_t)h * SEQ + m0 + s) * DHD + d0;
            }
            bf16x8 v0, v1;
            #pragma unroll
            for (int d = 0; d < 8; ++d) v0[d] = oT[d * 12 + h][s];
            #pragma unroll
            for (int d = 0; d < 8; ++d) v1[d] = oT[(8 + d) * 12 + h][s];
            *reinterpret_cast<bf16x8*>(&outp[base])     = v0;
            *reinterpret_cast<bf16x8*>(&outp[base + 8]) = v1;
        }
    }
}

// ---------------------------------------------------------------------------
// Kernel 2: softmax stats (m, l). Barrier-free: each wave owns 16 rows and
// loads its own K fragments straight from global (L2-resident).
// grid (32, 12, 3): bb in {0,1} content per batch; bb==2 positional.
// ---------------------------------------------------------------------------
__global__ __launch_bounds__(256) void stats_kernel(
    const __bf16* __restrict__ Qi, const __bf16* __restrict__ Ki,
    const __bf16* __restrict__ Qp, const __bf16* __restrict__ Kp,
    float* __restrict__ m_ws, float* __restrict__ l_ws)
{
    const int it = blockIdx.x, h = blockIdx.y, bb = blockIdx.z;
    const int tid = threadIdx.x, lane = tid & 63, wv = tid >> 6;
    const int l15 = lane & 15, lg = lane >> 4;
    const int i0 = it * 64 + wv * 16;

    const __bf16* Q = (bb < 2) ? Qi + ((size_t)bb * NH + h) * SEQ * DHD
                               : Qp + (size_t)h * SEQ * DHD;
    const __bf16* K = (bb < 2) ? Ki + ((size_t)bb * NH + h) * SEQ * DHD
                               : Kp + (size_t)h * SEQ * DHD;

    bf16x8 a[2];
    #pragma unroll
    for (int ks = 0; ks < 2; ++ks)
        a[ks] = *reinterpret_cast<const bf16x8*>(
            &Q[(size_t)(i0 + l15) * DHD + ks * 32 + lg * 8]);

    float mr[4], lr[4];
    #pragma unroll
    for (int r = 0; r < 4; ++r) { mr[r] = -1e30f; lr[r] = 0.0f; }

    for (int jt = 0; jt < 32; ++jt) {
        const int j0 = jt * 64;
        bf16x8 bk[2][4];
        #pragma unroll
        for (int ks = 0; ks < 2; ++ks)
            #pragma unroll
            for (int nf = 0; nf < 4; ++nf)
                bk[ks][nf] = *reinterpret_cast<const bf16x8*>(
                    &K[(size_t)(j0 + nf * 16 + l15) * DHD + ks * 32 + lg * 8]);
        f32x4 c[4] = {};
        #pragma unroll
        for (int ks = 0; ks < 2; ++ks)
            #pragma unroll
            for (int nf = 0; nf < 4; ++nf)
                c[nf] = MFMA16(a[ks], bk[ks][nf], c[nf]);

        #pragma unroll
        for (int r = 0; r < 4; ++r) {
            const float x01 = fmaxf(c[0][r], c[1][r]);
            const float x23 = fmaxf(c[2][r], c[3][r]);
            const float mn = fmaxf(mr[r], fmaxf(x01, x23));
            lr[r] = lr[r] * __expf(mr[r] - mn)
                  + __expf(c[0][r] - mn) + __expf(c[1][r] - mn)
                  + __expf(c[2][r] - mn) + __expf(c[3][r] - mn);
            mr[r] = mn;
        }
    }

    #pragma unroll
    for (int msk = 1; msk < 16; msk <<= 1)
        #pragma unroll
        for (int r = 0; r < 4; ++r) {
            const float mo = __shfl_xor(mr[r], msk);
            const float lo = __shfl_xor(lr[r], msk);
            const float mn = fmaxf(mr[r], mo);
            lr[r] = lr[r] * __expf(mr[r] - mn) + lo * __expf(mo - mn);
            mr[r] = mn;
        }

    if (l15 == 0) {
        const size_t base = ((size_t)bb * NH + h) * SEQ + i0;
        #pragma unroll
        for (int r = 0; r < 4; ++r) {
            m_ws[base + lg * 4 + r] = mr[r];
            l_ws[base + lg * 4 + r] = lr[r];
        }
    }
}

// ---------------------------------------------------------------------------
// Kernel 3: emit blended probs + fused PV. Fully wave-independent main loop:
// each wave owns 3 heads for a 16-row i-tile and a 256-wide j chunk; it
// computes, softmaxes, blends, stores its own h-slices (3 dwords per (i,j)),
// and accumulates PV. Zero barriers in the j loop. grid (128, 8, 2).
// ---------------------------------------------------------------------------
__global__ __launch_bounds__(256) void emit_kernel(
    const __bf16* __restrict__ Qi, const __bf16* __restrict__ Ki,
    const __bf16* __restrict__ Qp, const __bf16* __restrict__ Kp,
    const __bf16* __restrict__ Vt,
    const float* __restrict__ m_ws, const float* __restrict__ l_ws,
    float* __restrict__ out1, float* __restrict__ attn_pre)
{
    const int it = blockIdx.x, js = blockIdx.y, b = blockIdx.z;
    const int i0 = it * 16;
    const int tid = threadIdx.x, lane = tid & 63, wv = tid >> 6;
    const int l15 = lane & 15, lg = lane >> 4;

    __shared__ __bf16 pbuf[4][3][16][40];   // wave-private, padded (bank spread)
    __shared__ float  mlb[4][3][16][4];     // wave-private {m_i, 0.5/l_i, m_p, 0.5/l_p}

    if (lane < 48) {
        const int hh = lane >> 4, i = lane & 15;
        const int h = wv * 3 + hh;
        const size_t bi  = ((size_t)b * NH + h) * SEQ + i0 + i;
        const size_t ppi = ((size_t)2 * NH + h) * SEQ + i0 + i;
        mlb[wv][hh][i][0] = m_ws[bi];
        mlb[wv][hh][i][1] = 0.5f / l_ws[bi];
        mlb[wv][hh][i][2] = m_ws[ppi];
        mlb[wv][hh][i][3] = 0.5f / l_ws[ppi];
    }
    __syncthreads();   // one-time; main loop is barrier-free

    // persistent Q fragments: [head][stream][kstep]
    bf16x8 aQ[3][2][2];
    #pragma unroll
    for (int hh = 0; hh < 3; ++hh) {
        const int h = wv * 3 + hh;
        #pragma unroll
        for (int ks = 0; ks < 2; ++ks) {
            aQ[hh][0][ks] = *reinterpret_cast<const bf16x8*>(
                &Qi[(((size_t)b * NH + h) * SEQ + i0 + l15) * DHD + ks * 32 + lg * 8]);
            aQ[hh][1][ks] = *reinterpret_cast<const bf16x8*>(
                &Qp[((size_t)h * SEQ + i0 + l15) * DHD + ks * 32 + lg * 8]);
        }
    }

    f32x4 acc[3][4] = {};   // PV accumulators: [head][d-frag]

    #pragma unroll 1
    for (int jt = 0; jt < 8; ++jt) {
        const int j0 = js * 256 + jt * 32;

        #pragma unroll
        for (int hh = 0; hh < 3; ++hh) {
            const int h = wv * 3 + hh;
            const __bf16* Kib = Ki + ((size_t)b * NH + h) * SEQ * DHD;
            const __bf16* Kpb = Kp + (size_t)h * SEQ * DHD;

            f32x4 ci[2] = {}, cq[2] = {};
            #pragma unroll
            for (int ks = 0; ks < 2; ++ks)
                #pragma unroll
                for (int nf = 0; nf < 2; ++nf) {
                    const bf16x8 bi_ = *reinterpret_cast<const bf16x8*>(
                        &Kib[(size_t)(j0 + nf * 16 + l15) * DHD + ks * 32 + lg * 8]);
                    const bf16x8 bp_ = *reinterpret_cast<const bf16x8*>(
                        &Kpb[(size_t)(j0 + nf * 16 + l15) * DHD + ks * 32 + lg * 8]);
                    ci[nf] = MFMA16(aQ[hh][0][ks], bi_, ci[nf]);
                    cq[nf] = MFMA16(aQ[hh][1][ks], bp_, cq[nf]);
                }

            // softmax + gamma blend -> wave-private pbuf slice
            #pragma unroll
            for (int r = 0; r < 4; ++r) {
                const int i = lg * 4 + r;
                const f32x4 mlv = *reinterpret_cast<const f32x4*>(&mlb[wv][hh][i][0]);
                #pragma unroll
                for (int nf = 0; nf < 2; ++nf) {
                    const float pi_ = __expf(ci[nf][r] - mlv[0]) * mlv[1];
                    const float pq_ = __expf(cq[nf][r] - mlv[2]) * mlv[3];
                    pbuf[wv][hh][i][nf * 16 + l15] = (__bf16)(pi_ + pq_);
                }
            }

            // PV (same-wave RAW through LDS; compiler inserts lgkmcnt)
            const bf16x8 ap = *reinterpret_cast<const bf16x8*>(&pbuf[wv][hh][l15][lg * 8]);
            #pragma unroll
            for (int nf = 0; nf < 4; ++nf) {
                const bf16x8 bv = *reinterpret_cast<const bf16x8*>(
                    &Vt[(((size_t)b * NH + h) * DHD + nf * 16 + l15) * SEQ + j0 + lg * 8]);
                acc[hh][nf] = MFMA16(ap, bv, acc[hh][nf]);
            }
        }

        // wave-private store: this wave's 3 heads for all 16x32 (i,j)
        #pragma unroll
        for (int p = 0; p < 8; ++p) {
            const int pair = p * 64 + lane;
            const int i = pair >> 5, jj = pair & 31;
            const size_t base =
                (((size_t)(b * SEQ + i0 + i)) * SEQ + j0 + jj) * 12 + wv * 3;
            out1[base + 0] = (float)pbuf[wv][0][i][jj];
            out1[base + 1] = (float)pbuf[wv][1][i][jj];
            out1[base + 2] = (float)pbuf[wv][2][i][jj];
        }
    }

    // PV epilogue: j-chunk partial sums -> atomicAdd
    #pragma unroll
    for (int hh = 0; hh < 3; ++hh) {
        const int h = wv * 3 + hh;
        #pragma unroll
        for (int nf = 0; nf < 4; ++nf)
            #pragma unroll
            for (int r = 0; r < 4; ++r) {
                const int i = lg * 4 + r;
                atomicAdd(&attn_pre[((size_t)(b * SEQ + i0 + i)) * DIM + h * DHD + nf * 16 + l15],
                          acc[hh][nf][r]);
            }
    }
}

// ---------------------------------------------------------------------------
// Kernel 4: final GEMM attn_pre (f32) @ Wo (f32) -> out0 (f32)
// ---------------------------------------------------------------------------
__global__ __launch_bounds__(256) void final_kernel(
    const float* __restrict__ A, const float* __restrict__ W, float* __restrict__ out0)
{
    const int m0 = blockIdx.y * 64;
    const int n0 = blockIdx.x * 192;

    __shared__ __bf16 Al[64][32];
    __shared__ __bf16 Wl[192][32];

    const int tid = threadIdx.x;
    const int lane = tid & 63, wv = tid >> 6;
    const int wm = wv >> 1, wn = wv & 1;
    const int l15 = lane & 15, lg = lane >> 4;

    f32x4 c[2][6] = {};

    for (int kt = 0; kt < 24; ++kt) {
        const int k0 = kt * 32;
        __syncthreads();
        {
            const int r = tid >> 3, kq = tid & 7;
            #pragma unroll
            for (int rep = 0; rep < 2; ++rep) {
                const float4 v = *reinterpret_cast<const float4*>(
                    &A[(size_t)(m0 + r + rep * 32) * DIM + k0 + kq * 4]);
                bf16x4 t;
                t[0] = (__bf16)v.x; t[1] = (__bf16)v.y; t[2] = (__bf16)v.z; t[3] = (__bf16)v.w;
                *reinterpret_cast<bf16x4*>(&Al[r + rep * 32][kq * 4]) = t;
            }
        }
        for (int idx = tid; idx < 32 * 48; idx += 256) {
            const int k = idx / 48, nq = idx - k * 48;
            const float4 v = *reinterpret_cast<const float4*>(
                &W[(size_t)(k0 + k) * DIM + n0 + nq * 4]);
            Wl[nq * 4 + 0][k] = (__bf16)v.x;
            Wl[nq * 4 + 1][k] = (__bf16)v.y;
            Wl[nq * 4 + 2][k] = (__bf16)v.z;
            Wl[nq * 4 + 3][k] = (__bf16)v.w;
        }
        __syncthreads();

        bf16x8 a[2], b[6];
        #pragma unroll
        for (int mf = 0; mf < 2; ++mf)
            a[mf] = *reinterpret_cast<const bf16x8*>(&Al[wm * 32 + mf * 16 + l15][lg * 8]);
        #pragma unroll
        for (int nf = 0; nf < 6; ++nf)
            b[nf] = *reinterpret_cast<const bf16x8*>(&Wl[wn * 96 + nf * 16 + l15][lg * 8]);
        #pragma unroll
        for (int mf = 0; mf < 2; ++mf)
            #pragma unroll
            for (int nf = 0; nf < 6; ++nf)
                c[mf][nf] = MFMA16(a[mf], b[nf], c[mf][nf]);
    }

    #pragma unroll
    for (int mf = 0; mf < 2; ++mf)
        #pragma unroll
        for (int nf = 0; nf < 6; ++nf)
            #pragma unroll
            for (int r = 0; r < 4; ++r) {
                const int m = m0 + wm * 32 + mf * 16 + lg * 4 + r;
                const int n = n0 + wn * 96 + nf * 16 + l15;
                out0[(size_t)m * DIM + n] = c[mf][nf][r];
            }
}

// ---------------------------------------------------------------------------
extern "C" void kernel_launch(void* const* d_in, const int* in_sizes, int n_in,
                              void* d_out, int out_size, void* d_ws, size_t ws_size,
                              hipStream_t stream)
{
    (void)in_sizes; (void)n_in; (void)out_size; (void)ws_size;

    const float* inp = (const float*)d_in[0];
    const float* pos = (const float*)d_in[1];
    const float* Wqi = (const float*)d_in[2];
    const float* Wki = (const float*)d_in[3];
    const float* Wqp = (const float*)d_in[4];
    const float* Wkp = (const float*)d_in[5];
    const float* Wvv = (const float*)d_in[6];
    const float* Wo  = (const float*)d_in[7];

    char* w = (char*)d_ws;
    __bf16* Qi = (__bf16*)w; w += (size_t)2 * NH * SEQ * DHD * 2;   // 6 MB
    __bf16* Ki = (__bf16*)w; w += (size_t)2 * NH * SEQ * DHD * 2;   // 6 MB
    __bf16* Vt = (__bf16*)w; w += (size_t)2 * NH * SEQ * DHD * 2;   // 6 MB ([b][h][d][s])
    __bf16* Qp = (__bf16*)w; w += (size_t)NH * SEQ * DHD * 2;       // 3 MB
    __bf16* Kp = (__bf16*)w; w += (size_t)NH * SEQ * DHD * 2;       // 3 MB
    float* m_ws = (float*)w; w += (size_t)3 * NH * SEQ * 4;         // 288 KB
    float* l_ws = (float*)w; w += (size_t)3 * NH * SEQ * 4;         // 288 KB
    float* attn_pre = (float*)w; w += (size_t)4096 * DIM * 4;       // 12 MB

    float* out0 = (float*)d_out;                  // [2,2048,768]
    float* out1 = out0 + (size_t)2 * SEQ * DIM;   // [2,2048,2048,12]

    hipMemsetAsync(attn_pre, 0, (size_t)4096 * DIM * 4, stream);

    hipLaunchKernelGGL(proj_kernel, dim3(4, 64, 5), dim3(256), 0, stream,
                       inp, pos, Wqi, Wki, Wqp, Wkp, Wvv, Qi, Ki, Vt, Qp, Kp);
    hipLaunchKernelGGL(stats_kernel, dim3(32, 12, 3), dim3(256), 0, stream,
                       Qi, Ki, Qp, Kp, m_ws, l_ws);
    hipLaunchKernelGGL(emit_kernel, dim3(128, 8, 2), dim3(256), 0, stream,
                       Qi, Ki, Qp, Kp, Vt, m_ws, l_ws, out1, attn_pre);
    hipLaunchKernelGGL(final_kernel, dim3(4, 64, 1), dim3(256), 0, stream,
                       attn_pre, Wo, out0);
}

// Round 3
// 891.544 us; speedup vs baseline: 1.1171x; 1.1171x over previous
//
#include <hip/hip_runtime.h>
#include <hip/hip_bf16.h>

// Problem constants
constexpr int NH  = 12;    // heads
constexpr int SEQ = 2048;  // sequence
constexpr int DHD = 64;    // head dim
constexpr int DIM = 768;   // model dim
// B = 2, GAMMA = 0.5. Scores are kept in log2 domain:
// Q-projection scale = 0.125 * log2(e), softmax uses exp2.
constexpr float QSCALE = 0.125f * 1.44269504088896f;

typedef __bf16 bf16x8 __attribute__((ext_vector_type(8)));
typedef __bf16 bf16x4 __attribute__((ext_vector_type(4)));
typedef float  f32x4  __attribute__((ext_vector_type(4)));

#define MFMA16(a, b, c) __builtin_amdgcn_mfma_f32_16x16x32_bf16((a), (b), (c), 0, 0, 0)

// ---------------------------------------------------------------------------
// Kernel 1: projections (R1 structure: simple scattered epilogue).
//   mode 0: out[((b*NH+h)*SEQ+s)*DHD+d]   (Qi / Ki)
//   mode 1: out[((b*NH+h)*DHD+d)*SEQ+s]   (V transposed)
//   mode 2: out[(h*SEQ+s)*DHD+d]          (Qp / Kp)
// ---------------------------------------------------------------------------
__global__ __launch_bounds__(256) void proj_kernel(
    const float* __restrict__ inp, const float* __restrict__ pos,
    const float* __restrict__ Wqi, const float* __restrict__ Wki,
    const float* __restrict__ Wqp, const float* __restrict__ Wkp,
    const float* __restrict__ Wvv,
    __bf16* __restrict__ Qi, __bf16* __restrict__ Ki, __bf16* __restrict__ Vt,
    __bf16* __restrict__ Qp, __bf16* __restrict__ Kp)
{
    const int z = blockIdx.z;
    const float* A; const float* W; __bf16* outp; int M; int mode; float scale = 1.0f;
    if (z == 0)      { A = inp; W = Wqi; outp = Qi; M = 4096; mode = 0; scale = QSCALE; }
    else if (z == 1) { A = inp; W = Wki; outp = Ki; M = 4096; mode = 0; }
    else if (z == 2) { A = inp; W = Wvv; outp = Vt; M = 4096; mode = 1; }
    else if (z == 3) { A = pos; W = Wqp; outp = Qp; M = 2048; mode = 2; scale = QSCALE; }
    else             { A = pos; W = Wkp; outp = Kp; M = 2048; mode = 2; }

    const int m0 = blockIdx.y * 64;
    if (m0 >= M) return;
    const int n0 = blockIdx.x * 192;

    __shared__ __bf16 Al[64][32];
    __shared__ __bf16 Wl[192][32];   // transposed: Wl[n_local][k_local]

    const int tid = threadIdx.x;
    const int lane = tid & 63, wv = tid >> 6;
    const int wm = wv >> 1, wn = wv & 1;
    const int l15 = lane & 15, lg = lane >> 4;

    f32x4 c[2][6] = {};

    for (int kt = 0; kt < 24; ++kt) {
        const int k0 = kt * 32;
        __syncthreads();
        {   // stage A tile 64x32 (f32 -> bf16)
            const int r = tid >> 3, kq = tid & 7;
            #pragma unroll
            for (int rep = 0; rep < 2; ++rep) {
                const float4 v = *reinterpret_cast<const float4*>(
                    &A[(size_t)(m0 + r + rep * 32) * DIM + k0 + kq * 4]);
                bf16x4 t;
                t[0] = (__bf16)v.x; t[1] = (__bf16)v.y; t[2] = (__bf16)v.z; t[3] = (__bf16)v.w;
                *reinterpret_cast<bf16x4*>(&Al[r + rep * 32][kq * 4]) = t;
            }
        }
        for (int idx = tid; idx < 32 * 48; idx += 256) {
            const int k = idx / 48, nq = idx - k * 48;
            const float4 v = *reinterpret_cast<const float4*>(
                &W[(size_t)(k0 + k) * DIM + n0 + nq * 4]);
            Wl[nq * 4 + 0][k] = (__bf16)v.x;
            Wl[nq * 4 + 1][k] = (__bf16)v.y;
            Wl[nq * 4 + 2][k] = (__bf16)v.z;
            Wl[nq * 4 + 3][k] = (__bf16)v.w;
        }
        __syncthreads();

        bf16x8 a[2], b[6];
        #pragma unroll
        for (int mf = 0; mf < 2; ++mf)
            a[mf] = *reinterpret_cast<const bf16x8*>(&Al[wm * 32 + mf * 16 + l15][lg * 8]);
        #pragma unroll
        for (int nf = 0; nf < 6; ++nf)
            b[nf] = *reinterpret_cast<const bf16x8*>(&Wl[wn * 96 + nf * 16 + l15][lg * 8]);
        #pragma unroll
        for (int mf = 0; mf < 2; ++mf)
            #pragma unroll
            for (int nf = 0; nf < 6; ++nf)
                c[mf][nf] = MFMA16(a[mf], b[nf], c[mf][nf]);
    }

    #pragma unroll
    for (int mf = 0; mf < 2; ++mf)
        #pragma unroll
        for (int nf = 0; nf < 6; ++nf)
            #pragma unroll
            for (int r = 0; r < 4; ++r) {
                const int m = m0 + wm * 32 + mf * 16 + lg * 4 + r;
                const int n = n0 + wn * 96 + nf * 16 + l15;
                const float val = c[mf][nf][r] * scale;
                const int d = n / 12, hh = n - d * 12;
                size_t idx;
                if (mode == 0) {
                    const int b_ = m >> 11, s_ = m & 2047;
                    idx = (((size_t)b_ * NH + hh) * SEQ + s_) * DHD + d;
                } else if (mode == 1) {
                    const int b_ = m >> 11, s_ = m & 2047;
                    idx = (((size_t)b_ * NH + hh) * DHD + d) * SEQ + s_;
                } else {
                    idx = ((size_t)hh * SEQ + m) * DHD + d;
                }
                outp[idx] = (__bf16)val;
            }
}

// ---------------------------------------------------------------------------
// Kernel 2: softmax stats (m, l), log2 domain. Single-wave blocks, zero
// barriers, zero LDS; each wave owns 32 rows x all j with 16 independent
// MFMA chains per iter. grid (64, 12, 3); bb in {0,1} content, 2 positional.
// ---------------------------------------------------------------------------
__global__ __launch_bounds__(64) void stats_kernel(
    const __bf16* __restrict__ Qi, const __bf16* __restrict__ Ki,
    const __bf16* __restrict__ Qp, const __bf16* __restrict__ Kp,
    float* __restrict__ m_ws, float* __restrict__ l_ws)
{
    const int bx = blockIdx.x, h = blockIdx.y, bb = blockIdx.z;
    const int lane = threadIdx.x;
    const int l15 = lane & 15, lg = lane >> 4;
    const int i0 = bx * 32;

    const __bf16* Q = (bb < 2) ? Qi + ((size_t)bb * NH + h) * SEQ * DHD
                               : Qp + (size_t)h * SEQ * DHD;
    const __bf16* K = (bb < 2) ? Ki + ((size_t)bb * NH + h) * SEQ * DHD
                               : Kp + (size_t)h * SEQ * DHD;

    bf16x8 a[2][2];   // [mf][ks]
    #pragma unroll
    for (int mf = 0; mf < 2; ++mf)
        #pragma unroll
        for (int ks = 0; ks < 2; ++ks)
            a[mf][ks] = *reinterpret_cast<const bf16x8*>(
                &Q[(size_t)(i0 + mf * 16 + l15) * DHD + ks * 32 + lg * 8]);

    float mr[2][4], lr[2][4];
    #pragma unroll
    for (int mf = 0; mf < 2; ++mf)
        #pragma unroll
        for (int r = 0; r < 4; ++r) { mr[mf][r] = -1e30f; lr[mf][r] = 0.0f; }

    for (int jt = 0; jt < 32; ++jt) {
        const int j0 = jt * 64;
        bf16x8 bk[2][4];   // [ks][nf] — shared by both m-frags
        #pragma unroll
        for (int ks = 0; ks < 2; ++ks)
            #pragma unroll
            for (int nf = 0; nf < 4; ++nf)
                bk[ks][nf] = *reinterpret_cast<const bf16x8*>(
                    &K[(size_t)(j0 + nf * 16 + l15) * DHD + ks * 32 + lg * 8]);
        f32x4 c[2][4] = {};
        #pragma unroll
        for (int ks = 0; ks < 2; ++ks)
            #pragma unroll
            for (int nf = 0; nf < 4; ++nf)
                #pragma unroll
                for (int mf = 0; mf < 2; ++mf)
                    c[mf][nf] = MFMA16(a[mf][ks], bk[ks][nf], c[mf][nf]);

        #pragma unroll
        for (int mf = 0; mf < 2; ++mf)
            #pragma unroll
            for (int r = 0; r < 4; ++r) {
                const float x01 = fmaxf(c[mf][0][r], c[mf][1][r]);
                const float x23 = fmaxf(c[mf][2][r], c[mf][3][r]);
                const float mn = fmaxf(mr[mf][r], fmaxf(x01, x23));
                lr[mf][r] = lr[mf][r] * exp2f(mr[mf][r] - mn)
                          + exp2f(c[mf][0][r] - mn) + exp2f(c[mf][1][r] - mn)
                          + exp2f(c[mf][2][r] - mn) + exp2f(c[mf][3][r] - mn);
                mr[mf][r] = mn;
            }
    }

    #pragma unroll
    for (int msk = 1; msk < 16; msk <<= 1)
        #pragma unroll
        for (int mf = 0; mf < 2; ++mf)
            #pragma unroll
            for (int r = 0; r < 4; ++r) {
                const float mo = __shfl_xor(mr[mf][r], msk);
                const float lo = __shfl_xor(lr[mf][r], msk);
                const float mn = fmaxf(mr[mf][r], mo);
                lr[mf][r] = lr[mf][r] * exp2f(mr[mf][r] - mn) + lo * exp2f(mo - mn);
                mr[mf][r] = mn;
            }

    if (l15 == 0) {
        const size_t base = ((size_t)bb * NH + h) * SEQ + i0;
        #pragma unroll
        for (int mf = 0; mf < 2; ++mf)
            #pragma unroll
            for (int r = 0; r < 4; ++r) {
                m_ws[base + mf * 16 + lg * 4 + r] = mr[mf][r];
                l_ws[base + mf * 16 + lg * 4 + r] = lr[mf][r];
            }
    }
}

// ---------------------------------------------------------------------------
// Kernel 3: emit blended probs + fused PV. R1's cooperative full-line store
// (no write amplification) + double-buffered pbuf (ONE barrier per j-step)
// + 40-pad rows (<=2-way LDS aliasing) + nontemporal out1 stores.
// grid (128, 8, 2); 4 waves; wave w owns heads 3w..3w+2.
// ---------------------------------------------------------------------------
__global__ __launch_bounds__(256) void emit_kernel(
    const __bf16* __restrict__ Qi, const __bf16* __restrict__ Ki,
    const __bf16* __restrict__ Qp, const __bf16* __restrict__ Kp,
    const __bf16* __restrict__ Vt,
    const float* __restrict__ m_ws, const float* __restrict__ l_ws,
    float* __restrict__ out1, float* __restrict__ attn_pre)
{
    const int it = blockIdx.x, js = blockIdx.y, b = blockIdx.z;
    const int i0 = it * 16;
    const int tid = threadIdx.x, lane = tid & 63, wv = tid >> 6;
    const int l15 = lane & 15, lg = lane >> 4;

    __shared__ __align__(16) __bf16 pbuf[2][12][16][40];  // double-buffered
    __shared__ float ml[12][16][4];   // {m_i, 0.5/l_i, m_p, 0.5/l_p}

    if (tid < 192) {
        const int h = tid >> 4, i = tid & 15;
        const size_t bi  = ((size_t)b * NH + h) * SEQ + i0 + i;
        const size_t ppi = ((size_t)2 * NH + h) * SEQ + i0 + i;
        ml[h][i][0] = m_ws[bi];
        ml[h][i][1] = 0.5f / l_ws[bi];
        ml[h][i][2] = m_ws[ppi];
        ml[h][i][3] = 0.5f / l_ws[ppi];
    }
    __syncthreads();

    // persistent Q fragments: [head][stream][kstep]
    bf16x8 aQ[3][2][2];
    #pragma unroll
    for (int hh = 0; hh < 3; ++hh) {
        const int h = wv * 3 + hh;
        #pragma unroll
        for (int ks = 0; ks < 2; ++ks) {
            aQ[hh][0][ks] = *reinterpret_cast<const bf16x8*>(
                &Qi[(((size_t)b * NH + h) * SEQ + i0 + l15) * DHD + ks * 32 + lg * 8]);
            aQ[hh][1][ks] = *reinterpret_cast<const bf16x8*>(
                &Qp[((size_t)h * SEQ + i0 + l15) * DHD + ks * 32 + lg * 8]);
        }
    }

    f32x4 acc[3][4] = {};   // PV accumulators: [head][d-frag]

    #pragma unroll 1
    for (int jt = 0; jt < 8; ++jt) {
        const int j0 = js * 256 + jt * 32;
        const int buf = jt & 1;

        #pragma unroll
        for (int hh = 0; hh < 3; ++hh) {
            const int h = wv * 3 + hh;
            const __bf16* Kib = Ki + ((size_t)b * NH + h) * SEQ * DHD;
            const __bf16* Kpb = Kp + (size_t)h * SEQ * DHD;

            f32x4 ci[2] = {}, cq[2] = {};
            #pragma unroll
            for (int ks = 0; ks < 2; ++ks)
                #pragma unroll
                for (int nf = 0; nf < 2; ++nf) {
                    const bf16x8 bi_ = *reinterpret_cast<const bf16x8*>(
                        &Kib[(size_t)(j0 + nf * 16 + l15) * DHD + ks * 32 + lg * 8]);
                    const bf16x8 bp_ = *reinterpret_cast<const bf16x8*>(
                        &Kpb[(size_t)(j0 + nf * 16 + l15) * DHD + ks * 32 + lg * 8]);
                    ci[nf] = MFMA16(aQ[hh][0][ks], bi_, ci[nf]);
                    cq[nf] = MFMA16(aQ[hh][1][ks], bp_, cq[nf]);
                }

            // softmax (log2 domain) + gamma blend -> pbuf[buf]
            #pragma unroll
            for (int r = 0; r < 4; ++r) {
                const int i = lg * 4 + r;
                const f32x4 mlv = *reinterpret_cast<const f32x4*>(&ml[h][i][0]);
                #pragma unroll
                for (int nf = 0; nf < 2; ++nf) {
                    const float pi_ = exp2f(ci[nf][r] - mlv[0]) * mlv[1];
                    const float pq_ = exp2f(cq[nf][r] - mlv[2]) * mlv[3];
                    pbuf[buf][h][i][nf * 16 + l15] = (__bf16)(pi_ + pq_);
                }
            }

            // PV (same-wave RAW through LDS)
            const bf16x8 ap = *reinterpret_cast<const bf16x8*>(&pbuf[buf][h][l15][lg * 8]);
            #pragma unroll
            for (int nf = 0; nf < 4; ++nf) {
                const bf16x8 bv = *reinterpret_cast<const bf16x8*>(
                    &Vt[(((size_t)b * NH + h) * DHD + nf * 16 + l15) * SEQ + j0 + lg * 8]);
                acc[hh][nf] = MFMA16(ap, bv, acc[hh][nf]);
            }
        }
        __syncthreads();   // pbuf[buf] complete (single barrier per j-step)

        // cooperative full-line store: 48 contiguous B per (i,j), nontemporal
        #pragma unroll
        for (int rep = 0; rep < 2; ++rep) {
            const int pair = rep * 256 + tid;
            const int i = pair >> 5, jj = pair & 31;
            const size_t base = (((size_t)(b * SEQ + i0 + i)) * SEQ + j0 + jj) * 12;
            f32x4 v0, v1, v2;
            #pragma unroll
            for (int q = 0; q < 4; ++q) {
                v0[q] = (float)pbuf[buf][q][i][jj];
                v1[q] = (float)pbuf[buf][4 + q][i][jj];
                v2[q] = (float)pbuf[buf][8 + q][i][jj];
            }
            __builtin_nontemporal_store(v0, reinterpret_cast<f32x4*>(&out1[base]));
            __builtin_nontemporal_store(v1, reinterpret_cast<f32x4*>(&out1[base + 4]));
            __builtin_nontemporal_store(v2, reinterpret_cast<f32x4*>(&out1[base + 8]));
        }
        // no second barrier: next iter writes pbuf[buf^1]; writes to pbuf[buf]
        // resume only after the NEXT barrier, which orders them after these reads.
    }

    // PV epilogue: j-chunk partial sums -> atomicAdd
    #pragma unroll
    for (int hh = 0; hh < 3; ++hh) {
        const int h = wv * 3 + hh;
        #pragma unroll
        for (int nf = 0; nf < 4; ++nf)
            #pragma unroll
            for (int r = 0; r < 4; ++r) {
                const int i = lg * 4 + r;
                atomicAdd(&attn_pre[((size_t)(b * SEQ + i0 + i)) * DIM + h * DHD + nf * 16 + l15],
                          acc[hh][nf][r]);
            }
    }
}

// ---------------------------------------------------------------------------
// Kernel 4: final GEMM attn_pre (f32) @ Wo (f32) -> out0 (f32)
// ---------------------------------------------------------------------------
__global__ __launch_bounds__(256) void final_kernel(
    const float* __restrict__ A, const float* __restrict__ W, float* __restrict__ out0)
{
    const int m0 = blockIdx.y * 64;
    const int n0 = blockIdx.x * 192;

    __shared__ __bf16 Al[64][32];
    __shared__ __bf16 Wl[192][32];

    const int tid = threadIdx.x;
    const int lane = tid & 63, wv = tid >> 6;
    const int wm = wv >> 1, wn = wv & 1;
    const int l15 = lane & 15, lg = lane >> 4;

    f32x4 c[2][6] = {};

    for (int kt = 0; kt < 24; ++kt) {
        const int k0 = kt * 32;
        __syncthreads();
        {
            const int r = tid >> 3, kq = tid & 7;
            #pragma unroll
            for (int rep = 0; rep < 2; ++rep) {
                const float4 v = *reinterpret_cast<const float4*>(
                    &A[(size_t)(m0 + r + rep * 32) * DIM + k0 + kq * 4]);
                bf16x4 t;
                t[0] = (__bf16)v.x; t[1] = (__bf16)v.y; t[2] = (__bf16)v.z; t[3] = (__bf16)v.w;
                *reinterpret_cast<bf16x4*>(&Al[r + rep * 32][kq * 4]) = t;
            }
        }
        for (int idx = tid; idx < 32 * 48; idx += 256) {
            const int k = idx / 48, nq = idx - k * 48;
            const float4 v = *reinterpret_cast<const float4*>(
                &W[(size_t)(k0 + k) * DIM + n0 + nq * 4]);
            Wl[nq * 4 + 0][k] = (__bf16)v.x;
            Wl[nq * 4 + 1][k] = (__bf16)v.y;
            Wl[nq * 4 + 2][k] = (__bf16)v.z;
            Wl[nq * 4 + 3][k] = (__bf16)v.w;
        }
        __syncthreads();

        bf16x8 a[2], b[6];
        #pragma unroll
        for (int mf = 0; mf < 2; ++mf)
            a[mf] = *reinterpret_cast<const bf16x8*>(&Al[wm * 32 + mf * 16 + l15][lg * 8]);
        #pragma unroll
        for (int nf = 0; nf < 6; ++nf)
            b[nf] = *reinterpret_cast<const bf16x8*>(&Wl[wn * 96 + nf * 16 + l15][lg * 8]);
        #pragma unroll
        for (int mf = 0; mf < 2; ++mf)
            #pragma unroll
            for (int nf = 0; nf < 6; ++nf)
                c[mf][nf] = MFMA16(a[mf], b[nf], c[mf][nf]);
    }

    #pragma unroll
    for (int mf = 0; mf < 2; ++mf)
        #pragma unroll
        for (int nf = 0; nf < 6; ++nf)
            #pragma unroll
            for (int r = 0; r < 4; ++r) {
                const int m = m0 + wm * 32 + mf * 16 + lg * 4 + r;
                const int n = n0 + wn * 96 + nf * 16 + l15;
                out0[(size_t)m * DIM + n] = c[mf][nf][r];
            }
}

// ---------------------------------------------------------------------------
extern "C" void kernel_launch(void* const* d_in, const int* in_sizes, int n_in,
                              void* d_out, int out_size, void* d_ws, size_t ws_size,
                              hipStream_t stream)
{
    (void)in_sizes; (void)n_in; (void)out_size; (void)ws_size;

    const float* inp = (const float*)d_in[0];
    const float* pos = (const float*)d_in[1];
    const float* Wqi = (const float*)d_in[2];
    const float* Wki = (const float*)d_in[3];
    const float* Wqp = (const float*)d_in[4];
    const float* Wkp = (const float*)d_in[5];
    const float* Wvv = (const float*)d_in[6];
    const float* Wo  = (const float*)d_in[7];

    char* w = (char*)d_ws;
    __bf16* Qi = (__bf16*)w; w += (size_t)2 * NH * SEQ * DHD * 2;   // 6 MB
    __bf16* Ki = (__bf16*)w; w += (size_t)2 * NH * SEQ * DHD * 2;   // 6 MB
    __bf16* Vt = (__bf16*)w; w += (size_t)2 * NH * SEQ * DHD * 2;   // 6 MB ([b][h][d][s])
    __bf16* Qp = (__bf16*)w; w += (size_t)NH * SEQ * DHD * 2;       // 3 MB
    __bf16* Kp = (__bf16*)w; w += (size_t)NH * SEQ * DHD * 2;       // 3 MB
    float* m_ws = (float*)w; w += (size_t)3 * NH * SEQ * 4;         // 288 KB
    float* l_ws = (float*)w; w += (size_t)3 * NH * SEQ * 4;         // 288 KB
    float* attn_pre = (float*)w; w += (size_t)4096 * DIM * 4;       // 12 MB

    float* out0 = (float*)d_out;                  // [2,2048,768]
    float* out1 = out0 + (size_t)2 * SEQ * DIM;   // [2,2048,2048,12]

    hipMemsetAsync(attn_pre, 0, (size_t)4096 * DIM * 4, stream);

    hipLaunchKernelGGL(proj_kernel, dim3(4, 64, 5), dim3(256), 0, stream,
                       inp, pos, Wqi, Wki, Wqp, Wkp, Wvv, Qi, Ki, Vt, Qp, Kp);
    hipLaunchKernelGGL(stats_kernel, dim3(64, 12, 3), dim3(64), 0, stream,
                       Qi, Ki, Qp, Kp, m_ws, l_ws);
    hipLaunchKernelGGL(emit_kernel, dim3(128, 8, 2), dim3(256), 0, stream,
                       Qi, Ki, Qp, Kp, Vt, m_ws, l_ws, out1, attn_pre);
    hipLaunchKernelGGL(final_kernel, dim3(4, 64, 1), dim3(256), 0, stream,
                       attn_pre, Wo, out0);
}

// Round 4
// 734.146 us; speedup vs baseline: 1.3566x; 1.2144x over previous
//
#include <hip/hip_runtime.h>
#include <hip/hip_bf16.h>

// Problem constants
constexpr int NH  = 12;    // heads
constexpr int SEQ = 2048;  // sequence
constexpr int DHD = 64;    // head dim
constexpr int DIM = 768;   // model dim
// B = 2, GAMMA = 0.5. Scores kept in log2 domain: QSCALE folded into packed Wq.
constexpr float QSCALE = 0.125f * 1.44269504088896f;

typedef __bf16 bf16x8 __attribute__((ext_vector_type(8)));
typedef __bf16 bf16x4 __attribute__((ext_vector_type(4)));
typedef float  f32x4  __attribute__((ext_vector_type(4)));

#define MFMA16(a, b, c) __builtin_amdgcn_mfma_f32_16x16x32_bf16((a), (b), (c), 0, 0, 0)

// ---------------------------------------------------------------------------
// Kernel 0a: convert inp (4096x768) and pos (2048x768) f32 -> bf16, same layout.
// ---------------------------------------------------------------------------
__global__ __launch_bounds__(256) void conv_kernel(
    const float* __restrict__ inp, const float* __restrict__ pos,
    __bf16* __restrict__ Ab, __bf16* __restrict__ Pb)
{
    const int idx = blockIdx.x * 256 + threadIdx.x;   // one bf16x8 per thread
    constexpr int N8I = 4096 * 768 / 8;               // 393216
    constexpr int N8P = 2048 * 768 / 8;               // 196608
    if (idx >= N8I + N8P) return;
    const float* src; __bf16* dst; int off;
    if (idx < N8I) { src = inp; dst = Ab; off = idx; }
    else           { src = pos; dst = Pb; off = idx - N8I; }
    const float4 v0 = *reinterpret_cast<const float4*>(&src[(size_t)off * 8]);
    const float4 v1 = *reinterpret_cast<const float4*>(&src[(size_t)off * 8 + 4]);
    bf16x8 t;
    t[0] = (__bf16)v0.x; t[1] = (__bf16)v0.y; t[2] = (__bf16)v0.z; t[3] = (__bf16)v0.w;
    t[4] = (__bf16)v1.x; t[5] = (__bf16)v1.y; t[6] = (__bf16)v1.z; t[7] = (__bf16)v1.w;
    *reinterpret_cast<bf16x8*>(&dst[(size_t)off * 8]) = t;
}

// ---------------------------------------------------------------------------
// Kernel 0b: pack W -> Wp[z][h][d][k] bf16 (head-deinterleaved, B^T layout for
// direct MFMA B-fragment loads), QSCALE folded into z in {0,3}.
// grid (12 k-tiles, 12 h, 5 z), block 256.
// ---------------------------------------------------------------------------
__global__ __launch_bounds__(256) void packw_kernel(
    const float* __restrict__ Wqi, const float* __restrict__ Wki,
    const float* __restrict__ Wvv, const float* __restrict__ Wqp,
    const float* __restrict__ Wkp, __bf16* __restrict__ Wp)
{
    const int kt = blockIdx.x, h = blockIdx.y, z = blockIdx.z;
    const int k0 = kt * 64;
    const float* W; float scale = 1.0f;
    if (z == 0)      { W = Wqi; scale = QSCALE; }
    else if (z == 1) { W = Wki; }
    else if (z == 2) { W = Wvv; }
    else if (z == 3) { W = Wqp; scale = QSCALE; }
    else             { W = Wkp; }

    __shared__ __bf16 lds[64][68];
    const int tid = threadIdx.x;
    {   // read: lanes sweep d (stride-48B gather, L2-resident)
        const int d = tid & 63, kq = tid >> 6;
        #pragma unroll
        for (int rep = 0; rep < 16; ++rep) {
            const int kk = rep * 4 + kq;
            lds[kk][d] = (__bf16)(W[(size_t)(k0 + kk) * DIM + d * 12 + h] * scale);
        }
    }
    __syncthreads();
    {   // write: rows [d][k] coalesced (128 B per row)
        const int k = tid & 63, dq = tid >> 6;
        const size_t slab = ((size_t)z * 12 + h) * 64;
        #pragma unroll
        for (int rep = 0; rep < 16; ++rep) {
            const int d = rep * 4 + dq;
            Wp[(slab + d) * DIM + k0 + k] = lds[k][d];
        }
    }
}

// ---------------------------------------------------------------------------
// Kernel 1: projections — no LDS, no barriers. Register GEMM streaming A and
// packed-W B-fragments straight from L2. grid (16, 12, 5), block 256 (4 waves,
// each wave 64 rows). Output layout [slab][s][64] bf16, lane-coalesced stores.
// ---------------------------------------------------------------------------
__global__ __launch_bounds__(256) void proj_kernel(
    const __bf16* __restrict__ Ab, const __bf16* __restrict__ Pb,
    const __bf16* __restrict__ Wp,
    __bf16* __restrict__ Qi, __bf16* __restrict__ Ki, __bf16* __restrict__ Vsd,
    __bf16* __restrict__ Qp, __bf16* __restrict__ Kp)
{
    const int bx = blockIdx.x, h = blockIdx.y, z = blockIdx.z;
    if (z >= 3 && bx >= 8) return;
    const int tid = threadIdx.x, lane = tid & 63, wv = tid >> 6;
    const int l15 = lane & 15, lg = lane >> 4;
    const int m_w = bx * 256 + wv * 64;

    const __bf16* Asrc = (z < 3) ? Ab : Pb;
    const __bf16* Wsl = Wp + ((size_t)z * 12 + h) * 64 * DIM;

    f32x4 acc[4][4] = {};

    for (int kt = 0; kt < 24; ++kt) {
        const int k0 = kt * 32;
        bf16x8 a[4], b[4];
        #pragma unroll
        for (int mf = 0; mf < 4; ++mf)
            a[mf] = *reinterpret_cast<const bf16x8*>(
                &Asrc[(size_t)(m_w + mf * 16 + l15) * DIM + k0 + lg * 8]);
        #pragma unroll
        for (int nf = 0; nf < 4; ++nf)
            b[nf] = *reinterpret_cast<const bf16x8*>(
                &Wsl[(size_t)(nf * 16 + l15) * DIM + k0 + lg * 8]);
        #pragma unroll
        for (int mf = 0; mf < 4; ++mf)
            #pragma unroll
            for (int nf = 0; nf < 4; ++nf)
                acc[mf][nf] = MFMA16(a[mf], b[nf], acc[mf][nf]);
    }

    __bf16* outp = (z == 0) ? Qi : (z == 1) ? Ki : (z == 2) ? Vsd : (z == 3) ? Qp : Kp;
    #pragma unroll
    for (int mf = 0; mf < 4; ++mf)
        #pragma unroll
        for (int r = 0; r < 4; ++r) {
            const int m = m_w + mf * 16 + lg * 4 + r;
            const int s = m & 2047;
            const int slab = (z < 3) ? ((m >> 11) * 12 + h) : h;
            const size_t base = ((size_t)slab * SEQ + s) * DHD;
            #pragma unroll
            for (int nf = 0; nf < 4; ++nf)
                outp[base + nf * 16 + l15] = (__bf16)acc[mf][nf][r];
        }
}

// ---------------------------------------------------------------------------
// Kernel 1b: V transpose  Vsd[slab][s][d] -> Vt[slab][d][s]. grid (32, 24).
// ---------------------------------------------------------------------------
__global__ __launch_bounds__(256) void vtrans_kernel(
    const __bf16* __restrict__ Vsd, __bf16* __restrict__ Vt)
{
    const int s0 = blockIdx.x * 64, slab = blockIdx.y;
    __shared__ __bf16 lds[64][66];
    const int tid = threadIdx.x;
    {
        const int rr = tid >> 3, cq = tid & 7;
        #pragma unroll
        for (int rep = 0; rep < 2; ++rep) {
            const int r2 = rr + rep * 32;
            *reinterpret_cast<bf16x8*>(&lds[r2][cq * 8]) =
                *reinterpret_cast<const bf16x8*>(
                    &Vsd[((size_t)slab * SEQ + s0 + r2) * DHD + cq * 8]);
        }
    }
    __syncthreads();
    {
        const int dd = tid >> 3, sq = tid & 7;
        #pragma unroll
        for (int rep = 0; rep < 2; ++rep) {
            const int d2 = dd + rep * 32;
            bf16x8 v;
            #pragma unroll
            for (int q = 0; q < 8; ++q) v[q] = lds[sq * 8 + q][d2];
            *reinterpret_cast<bf16x8*>(&Vt[((size_t)slab * DHD + d2) * SEQ + s0 + sq * 8]) = v;
        }
    }
}

// ---------------------------------------------------------------------------
// Kernel 2: softmax stats (m, l), log2 domain. 16 rows per single-wave block
// (2x parallelism vs R3). grid (128, 12, 3); bb in {0,1} content, 2 positional.
// ---------------------------------------------------------------------------
__global__ __launch_bounds__(64) void stats_kernel(
    const __bf16* __restrict__ Qi, const __bf16* __restrict__ Ki,
    const __bf16* __restrict__ Qp, const __bf16* __restrict__ Kp,
    float* __restrict__ m_ws, float* __restrict__ l_ws)
{
    const int bx = blockIdx.x, h = blockIdx.y, bb = blockIdx.z;
    const int lane = threadIdx.x;
    const int l15 = lane & 15, lg = lane >> 4;
    const int i0 = bx * 16;

    const __bf16* Q = (bb < 2) ? Qi + ((size_t)bb * NH + h) * SEQ * DHD
                               : Qp + (size_t)h * SEQ * DHD;
    const __bf16* K = (bb < 2) ? Ki + ((size_t)bb * NH + h) * SEQ * DHD
                               : Kp + (size_t)h * SEQ * DHD;

    bf16x8 a[2];
    #pragma unroll
    for (int ks = 0; ks < 2; ++ks)
        a[ks] = *reinterpret_cast<const bf16x8*>(
            &Q[(size_t)(i0 + l15) * DHD + ks * 32 + lg * 8]);

    float mr[4], lr[4];
    #pragma unroll
    for (int r = 0; r < 4; ++r) { mr[r] = -1e30f; lr[r] = 0.0f; }

    for (int jt = 0; jt < 32; ++jt) {
        const int j0 = jt * 64;
        bf16x8 bk[2][4];
        #pragma unroll
        for (int ks = 0; ks < 2; ++ks)
            #pragma unroll
            for (int nf = 0; nf < 4; ++nf)
                bk[ks][nf] = *reinterpret_cast<const bf16x8*>(
                    &K[(size_t)(j0 + nf * 16 + l15) * DHD + ks * 32 + lg * 8]);
        f32x4 c[4] = {};
        #pragma unroll
        for (int ks = 0; ks < 2; ++ks)
            #pragma unroll
            for (int nf = 0; nf < 4; ++nf)
                c[nf] = MFMA16(a[ks], bk[ks][nf], c[nf]);

        #pragma unroll
        for (int r = 0; r < 4; ++r) {
            const float x01 = fmaxf(c[0][r], c[1][r]);
            const float x23 = fmaxf(c[2][r], c[3][r]);
            const float mn = fmaxf(mr[r], fmaxf(x01, x23));
            lr[r] = lr[r] * exp2f(mr[r] - mn)
                  + exp2f(c[0][r] - mn) + exp2f(c[1][r] - mn)
                  + exp2f(c[2][r] - mn) + exp2f(c[3][r] - mn);
            mr[r] = mn;
        }
    }

    #pragma unroll
    for (int msk = 1; msk < 16; msk <<= 1)
        #pragma unroll
        for (int r = 0; r < 4; ++r) {
            const float mo = __shfl_xor(mr[r], msk);
            const float lo = __shfl_xor(lr[r], msk);
            const float mn = fmaxf(mr[r], mo);
            lr[r] = lr[r] * exp2f(mr[r] - mn) + lo * exp2f(mo - mn);
            mr[r] = mn;
        }

    if (l15 == 0) {
        const size_t base = ((size_t)bb * NH + h) * SEQ + i0;
        #pragma unroll
        for (int r = 0; r < 4; ++r) {
            m_ws[base + lg * 4 + r] = mr[r];
            l_ws[base + lg * 4 + r] = lr[r];
        }
    }
}

// ---------------------------------------------------------------------------
// Kernel 3: emit blended probs + fused PV. 6 waves x 2 heads, in-place K
// prefetch (K regs for step t+1 reloaded right after step t's QK MFMAs; loads
// hide under softmax+PV). Cooperative full-line out1 stores (no nt).
// grid (128, 8, 2), block 384.
// ---------------------------------------------------------------------------
__global__ __launch_bounds__(384) void emit_kernel(
    const __bf16* __restrict__ Qi, const __bf16* __restrict__ Ki,
    const __bf16* __restrict__ Qp, const __bf16* __restrict__ Kp,
    const __bf16* __restrict__ Vt,
    const float* __restrict__ m_ws, const float* __restrict__ l_ws,
    float* __restrict__ out1, float* __restrict__ attn_pre)
{
    const int it = blockIdx.x, js = blockIdx.y, b = blockIdx.z;
    const int i0 = it * 16;
    const int tid = threadIdx.x, lane = tid & 63, wv = tid >> 6;   // wv 0..5
    const int l15 = lane & 15, lg = lane >> 4;

    __shared__ __align__(16) __bf16 pbuf[2][12][16][40];
    __shared__ float ml[12][16][4];   // {m_i, 0.5/l_i, m_p, 0.5/l_p}

    if (tid < 192) {
        const int h = tid >> 4, i = tid & 15;
        const size_t bi  = ((size_t)b * NH + h) * SEQ + i0 + i;
        const size_t ppi = ((size_t)2 * NH + h) * SEQ + i0 + i;
        ml[h][i][0] = m_ws[bi];
        ml[h][i][1] = 0.5f / l_ws[bi];
        ml[h][i][2] = m_ws[ppi];
        ml[h][i][3] = 0.5f / l_ws[ppi];
    }
    __syncthreads();

    // per-wave head pair
    const __bf16* Kb[2][2];
    bf16x8 aQ[2][2][2];   // [hh][stream][ks]
    #pragma unroll
    for (int hh = 0; hh < 2; ++hh) {
        const int h = wv * 2 + hh;
        Kb[hh][0] = Ki + ((size_t)b * NH + h) * SEQ * DHD;
        Kb[hh][1] = Kp + (size_t)h * SEQ * DHD;
        #pragma unroll
        for (int ks = 0; ks < 2; ++ks) {
            aQ[hh][0][ks] = *reinterpret_cast<const bf16x8*>(
                &Qi[(((size_t)b * NH + h) * SEQ + i0 + l15) * DHD + ks * 32 + lg * 8]);
            aQ[hh][1][ks] = *reinterpret_cast<const bf16x8*>(
                &Qp[((size_t)h * SEQ + i0 + l15) * DHD + ks * 32 + lg * 8]);
        }
    }

    bf16x8 kf[2][2][2][2];   // [hh][stream][nf][ks] — current step's K frags
    {
        const int j0 = js * 256;
        #pragma unroll
        for (int hh = 0; hh < 2; ++hh)
            #pragma unroll
            for (int st = 0; st < 2; ++st)
                #pragma unroll
                for (int nf = 0; nf < 2; ++nf)
                    #pragma unroll
                    for (int ks = 0; ks < 2; ++ks)
                        kf[hh][st][nf][ks] = *reinterpret_cast<const bf16x8*>(
                            &Kb[hh][st][(size_t)(j0 + nf * 16 + l15) * DHD + ks * 32 + lg * 8]);
    }

    f32x4 acc[2][4] = {};   // PV accumulators [hh][d-frag]

    #pragma unroll 1
    for (int jt = 0; jt < 8; ++jt) {
        const int j0 = js * 256 + jt * 32;
        const int jn = (js * 256 + (jt + 1) * 32) & (SEQ - 1);   // wrap-safe prefetch
        const int buf = jt & 1;

        // QK^T for both heads, both streams (consumes kf)
        f32x4 ci[2][2] = {}, cq[2][2] = {};
        #pragma unroll
        for (int hh = 0; hh < 2; ++hh)
            #pragma unroll
            for (int ks = 0; ks < 2; ++ks)
                #pragma unroll
                for (int nf = 0; nf < 2; ++nf) {
                    ci[hh][nf] = MFMA16(aQ[hh][0][ks], kf[hh][0][nf][ks], ci[hh][nf]);
                    cq[hh][nf] = MFMA16(aQ[hh][1][ks], kf[hh][1][nf][ks], cq[hh][nf]);
                }

        // in-place prefetch of next step's K (WAR on kf; hides under softmax+PV)
        #pragma unroll
        for (int hh = 0; hh < 2; ++hh)
            #pragma unroll
            for (int st = 0; st < 2; ++st)
                #pragma unroll
                for (int nf = 0; nf < 2; ++nf)
                    #pragma unroll
                    for (int ks = 0; ks < 2; ++ks)
                        kf[hh][st][nf][ks] = *reinterpret_cast<const bf16x8*>(
                            &Kb[hh][st][(size_t)(jn + nf * 16 + l15) * DHD + ks * 32 + lg * 8]);

        // softmax (log2) + gamma blend -> pbuf[buf]
        #pragma unroll
        for (int hh = 0; hh < 2; ++hh) {
            const int h = wv * 2 + hh;
            #pragma unroll
            for (int r = 0; r < 4; ++r) {
                const int i = lg * 4 + r;
                const f32x4 mlv = *reinterpret_cast<const f32x4*>(&ml[h][i][0]);
                #pragma unroll
                for (int nf = 0; nf < 2; ++nf) {
                    const float pi_ = exp2f(ci[hh][nf][r] - mlv[0]) * mlv[1];
                    const float pq_ = exp2f(cq[hh][nf][r] - mlv[2]) * mlv[3];
                    pbuf[buf][h][i][nf * 16 + l15] = (__bf16)(pi_ + pq_);
                }
            }
        }

        // PV (same-wave RAW through LDS)
        #pragma unroll
        for (int hh = 0; hh < 2; ++hh) {
            const int h = wv * 2 + hh;
            const bf16x8 ap = *reinterpret_cast<const bf16x8*>(&pbuf[buf][h][l15][lg * 8]);
            #pragma unroll
            for (int nf = 0; nf < 4; ++nf) {
                const bf16x8 bv = *reinterpret_cast<const bf16x8*>(
                    &Vt[(((size_t)b * NH + h) * DHD + nf * 16 + l15) * SEQ + j0 + lg * 8]);
                acc[hh][nf] = MFMA16(ap, bv, acc[hh][nf]);
            }
        }
        __syncthreads();   // pbuf[buf] complete across all 6 waves

        // cooperative full-line store: 48 contiguous B per (i,j)
        for (int p = tid; p < 512; p += 384) {
            const int i = p >> 5, jj = p & 31;
            const size_t base = (((size_t)(b * SEQ + i0 + i)) * SEQ + j0 + jj) * 12;
            f32x4 v0, v1, v2;
            #pragma unroll
            for (int q = 0; q < 4; ++q) {
                v0[q] = (float)pbuf[buf][q][i][jj];
                v1[q] = (float)pbuf[buf][4 + q][i][jj];
                v2[q] = (float)pbuf[buf][8 + q][i][jj];
            }
            *reinterpret_cast<f32x4*>(&out1[base])     = v0;
            *reinterpret_cast<f32x4*>(&out1[base + 4]) = v1;
            *reinterpret_cast<f32x4*>(&out1[base + 8]) = v2;
        }
        // next iter writes pbuf[buf^1]; pbuf[buf] rewritten only after next barrier
    }

    // PV epilogue: j-chunk partial sums -> atomicAdd
    #pragma unroll
    for (int hh = 0; hh < 2; ++hh) {
        const int h = wv * 2 + hh;
        #pragma unroll
        for (int nf = 0; nf < 4; ++nf)
            #pragma unroll
            for (int r = 0; r < 4; ++r) {
                const int i = lg * 4 + r;
                atomicAdd(&attn_pre[((size_t)(b * SEQ + i0 + i)) * DIM + h * DHD + nf * 16 + l15],
                          acc[hh][nf][r]);
            }
    }
}

// ---------------------------------------------------------------------------
// Kernel 4: final GEMM attn_pre (f32) @ Wo (f32) -> out0 (f32)
// ---------------------------------------------------------------------------
__global__ __launch_bounds__(256) void final_kernel(
    const float* __restrict__ A, const float* __restrict__ W, float* __restrict__ out0)
{
    const int m0 = blockIdx.y * 64;
    const int n0 = blockIdx.x * 192;

    __shared__ __bf16 Al[64][32];
    __shared__ __bf16 Wl[192][32];

    const int tid = threadIdx.x;
    const int lane = tid & 63, wv = tid >> 6;
    const int wm = wv >> 1, wn = wv & 1;
    const int l15 = lane & 15, lg = lane >> 4;

    f32x4 c[2][6] = {};

    for (int kt = 0; kt < 24; ++kt) {
        const int k0 = kt * 32;
        __syncthreads();
        {
            const int r = tid >> 3, kq = tid & 7;
            #pragma unroll
            for (int rep = 0; rep < 2; ++rep) {
                const float4 v = *reinterpret_cast<const float4*>(
                    &A[(size_t)(m0 + r + rep * 32) * DIM + k0 + kq * 4]);
                bf16x4 t;
                t[0] = (__bf16)v.x; t[1] = (__bf16)v.y; t[2] = (__bf16)v.z; t[3] = (__bf16)v.w;
                *reinterpret_cast<bf16x4*>(&Al[r + rep * 32][kq * 4]) = t;
            }
        }
        for (int idx = tid; idx < 32 * 48; idx += 256) {
            const int k = idx / 48, nq = idx - k * 48;
            const float4 v = *reinterpret_cast<const float4*>(
                &W[(size_t)(k0 + k) * DIM + n0 + nq * 4]);
            Wl[nq * 4 + 0][k] = (__bf16)v.x;
            Wl[nq * 4 + 1][k] = (__bf16)v.y;
            Wl[nq * 4 + 2][k] = (__bf16)v.z;
            Wl[nq * 4 + 3][k] = (__bf16)v.w;
        }
        __syncthreads();

        bf16x8 a[2], b[6];
        #pragma unroll
        for (int mf = 0; mf < 2; ++mf)
            a[mf] = *reinterpret_cast<const bf16x8*>(&Al[wm * 32 + mf * 16 + l15][lg * 8]);
        #pragma unroll
        for (int nf = 0; nf < 6; ++nf)
            b[nf] = *reinterpret_cast<const bf16x8*>(&Wl[wn * 96 + nf * 16 + l15][lg * 8]);
        #pragma unroll
        for (int mf = 0; mf < 2; ++mf)
            #pragma unroll
            for (int nf = 0; nf < 6; ++nf)
                c[mf][nf] = MFMA16(a[mf], b[nf], c[mf][nf]);
    }

    #pragma unroll
    for (int mf = 0; mf < 2; ++mf)
        #pragma unroll
        for (int nf = 0; nf < 6; ++nf)
            #pragma unroll
            for (int r = 0; r < 4; ++r) {
                const int m = m0 + wm * 32 + mf * 16 + lg * 4 + r;
                const int n = n0 + wn * 96 + nf * 16 + l15;
                out0[(size_t)m * DIM + n] = c[mf][nf][r];
            }
}

// ---------------------------------------------------------------------------
extern "C" void kernel_launch(void* const* d_in, const int* in_sizes, int n_in,
                              void* d_out, int out_size, void* d_ws, size_t ws_size,
                              hipStream_t stream)
{
    (void)in_sizes; (void)n_in; (void)out_size; (void)ws_size;

    const float* inp = (const float*)d_in[0];
    const float* pos = (const float*)d_in[1];
    const float* Wqi = (const float*)d_in[2];
    const float* Wki = (const float*)d_in[3];
    const float* Wqp = (const float*)d_in[4];
    const float* Wkp = (const float*)d_in[5];
    const float* Wvv = (const float*)d_in[6];
    const float* Wo  = (const float*)d_in[7];

    char* w = (char*)d_ws;
    __bf16* Ab = (__bf16*)w;  w += (size_t)4096 * 768 * 2;          // 6 MB (dead after proj)
    __bf16* Pb = (__bf16*)w;  w += (size_t)2048 * 768 * 2;          // 3 MB
    __bf16* Wp = (__bf16*)w;  w += (size_t)5 * 768 * 768 * 2;       // 5.9 MB
    __bf16* Qi = (__bf16*)w;  w += (size_t)2 * NH * SEQ * DHD * 2;  // 6 MB
    __bf16* Ki = (__bf16*)w;  w += (size_t)2 * NH * SEQ * DHD * 2;  // 6 MB
    __bf16* Vsd = (__bf16*)w; w += (size_t)2 * NH * SEQ * DHD * 2;  // 6 MB
    __bf16* Qp = (__bf16*)w;  w += (size_t)NH * SEQ * DHD * 2;      // 3 MB
    __bf16* Kp = (__bf16*)w;  w += (size_t)NH * SEQ * DHD * 2;      // 3 MB
    float* m_ws = (float*)w;  w += (size_t)3 * NH * SEQ * 4;        // 288 KB
    float* l_ws = (float*)w;  w += (size_t)3 * NH * SEQ * 4;        // 288 KB
    float* attn_pre = (float*)w; w += (size_t)4096 * DIM * 4;       // 12 MB
    __bf16* Vt = Ab;   // alias: Ab is dead once proj completes; vtrans runs after

    float* out0 = (float*)d_out;                  // [2,2048,768]
    float* out1 = out0 + (size_t)2 * SEQ * DIM;   // [2,2048,2048,12]

    hipMemsetAsync(attn_pre, 0, (size_t)4096 * DIM * 4, stream);

    hipLaunchKernelGGL(conv_kernel, dim3(2304), dim3(256), 0, stream, inp, pos, Ab, Pb);
    hipLaunchKernelGGL(packw_kernel, dim3(12, 12, 5), dim3(256), 0, stream,
                       Wqi, Wki, Wvv, Wqp, Wkp, Wp);
    hipLaunchKernelGGL(proj_kernel, dim3(16, 12, 5), dim3(256), 0, stream,
                       Ab, Pb, Wp, Qi, Ki, Vsd, Qp, Kp);
    hipLaunchKernelGGL(vtrans_kernel, dim3(32, 24), dim3(256), 0, stream, Vsd, Vt);
    hipLaunchKernelGGL(stats_kernel, dim3(128, 12, 3), dim3(64), 0, stream,
                       Qi, Ki, Qp, Kp, m_ws, l_ws);
    hipLaunchKernelGGL(emit_kernel, dim3(128, 8, 2), dim3(384), 0, stream,
                       Qi, Ki, Qp, Kp, Vt, m_ws, l_ws, out1, attn_pre);
    hipLaunchKernelGGL(final_kernel, dim3(4, 64, 1), dim3(256), 0, stream,
                       attn_pre, Wo, out0);
}